// Round 2
// baseline (1481.706 us; speedup 1.0000x reference)
//
#include <hip/hip_runtime.h>
#include <hip/hip_cooperative_groups.h>
namespace cg = cooperative_groups;

#define DD     1024
#define HH     16
#define KVH    4
#define HDIM   64
#define NLAYER 6
#define FDIM   4096
#define VDIM   4096
#define NCODE  15
#define SS     16
#define KVDIM  256
#define EPSF   1e-6f

__device__ __forceinline__ float dot4(float4 a, float4 b){
  return a.x*b.x + a.y*b.y + a.z*b.z + a.w*b.w;
}
__device__ __forceinline__ float wave_sum(float v){
  #pragma unroll
  for (int o=32;o;o>>=1) v += __shfl_xor(v,o);
  return v;
}
__device__ __forceinline__ float grp16_sum(float v){
  #pragma unroll
  for (int o=8;o;o>>=1) v += __shfl_xor(v,o);
  return v;
}
__device__ __forceinline__ float grp16_max(float v){
  #pragma unroll
  for (int o=8;o;o>>=1) v = fmaxf(v, __shfl_xor(v,o));
  return v;
}

struct KP {
  const float *emb, *kcache, *pmask, *umask, *vcache, *invf;
  const float *Wq, *Wk, *Wv, *Wo, *ln1, *ln2, *qn, *kn, *Wg, *Wu, *Wd, *nw, *lmw;
  const int   *clen;
  float *hidden, *qkv, *act, *knew, *vnew;
  float *out_logits, *out_hidden, *out_nkc, *out_nvc;
};

// one persistent cooperative kernel: 256 blocks x 1024 threads (16 waves/CU)
__global__ __launch_bounds__(1024) void k_decode(KP p)
{
  cg::grid_group grid = cg::this_grid();
  const int t    = threadIdx.x;          // 0..1023
  const int b    = blockIdx.x;           // 0..255
  const int lane = t & 63, wid = t >> 6; // wid 0..15
  const int gw   = (b << 4) + wid;       // global wave id 0..4095

  __shared__ float xs[FDIM];             // staging: normed hidden (1024) / act (4096)
  __shared__ float qsh[DD];
  __shared__ float aosh[DD];
  __shared__ float ksh[KVDIM], vsh[KVDIM];
  __shared__ float awsh[HH*SS];
  __shared__ float umsh[SS], pmsh[SS];
  __shared__ float red[16];

  const float pos = (float)p.clen[0];

  #pragma unroll 1
  for (int l = 0; l < NLAYER; l++){
    const float* Wq_l = p.Wq + (size_t)l*DD*DD;
    const float* Wk_l = p.Wk + (size_t)l*KVDIM*DD;
    const float* Wv_l = p.Wv + (size_t)l*KVDIM*DD;
    const float* Wo_l = p.Wo + (size_t)l*DD*DD;
    const float* Wg_l = p.Wg + (size_t)l*FDIM*DD;
    const float* Wu_l = p.Wu + (size_t)l*FDIM*DD;
    const float* Wd_l = p.Wd + (size_t)l*DD*FDIM;
    const float* kc_l = p.kcache + (size_t)l*KVDIM*SS;
    const float* vc_l = p.vcache + (size_t)l*KVDIM*SS;
    const float* hsrc = (l == 0) ? p.emb : p.hidden;

    // ======== stage 1: rms(ln1) + QKV matvec (1536 rows, wave/row) ========
    {
      float hv = hsrc[t];
      float ss = wave_sum(hv*hv);
      if (lane == 0) red[wid] = ss;
      __syncthreads();
      float tot = 0.f;
      #pragma unroll
      for (int i=0;i<16;i++) tot += red[i];
      const float inv = rsqrtf(tot*(1.0f/DD) + EPSF);
      xs[t] = hv*inv*p.ln1[l*DD + t];
      __syncthreads();
    }
    if (gw < 1536){
      const float* Wrow = (gw < 1024) ? Wq_l + (size_t)gw*DD
                        : (gw < 1280) ? Wk_l + (size_t)(gw-1024)*DD
                                      : Wv_l + (size_t)(gw-1280)*DD;
      const float4* w4 = (const float4*)Wrow;
      const float4* x4 = (const float4*)xs;
      float acc = 0.f;
      #pragma unroll
      for (int j=0;j<4;j++) acc += dot4(w4[j*64+lane], x4[j*64+lane]);
      acc = wave_sum(acc);
      if (lane == 0) p.qkv[gw] = acc;
    }
    grid.sync();

    // ======== stage 2: attention (redundant per block) + Wo matvec ========
    if (t < SS){ umsh[t] = p.umask[t]; pmsh[t] = p.pmask[t]; }
    if (t < 256){   // q: per-head rms + rope -> qsh
      const int idx16 = t & 15;
      float4 q = ((const float4*)p.qkv)[t];
      float ss = grp16_sum(dot4(q,q));
      const float inv = rsqrtf(ss*(1.0f/HDIM) + EPSF);
      float4 w = ((const float4*)(p.qn + l*HDIM))[idx16];
      float x0=q.x*inv*w.x, x1=q.y*inv*w.y, x2=q.z*inv*w.z, x3=q.w*inv*w.w;
      float p0=__shfl_xor(x0,8), p1=__shfl_xor(x1,8), p2=__shfl_xor(x2,8), p3=__shfl_xor(x3,8);
      const int d0 = idx16*4;
      const bool lolane = (idx16 < 8);
      const int m = lolane ? d0 : d0-32;
      const float f0=p.invf[m]*pos, f1=p.invf[m+1]*pos, f2=p.invf[m+2]*pos, f3=p.invf[m+3]*pos;
      const float sgn = lolane ? -1.f : 1.f;
      float4 r;
      r.x = x0*cosf(f0) + sgn*p0*sinf(f0);
      r.y = x1*cosf(f1) + sgn*p1*sinf(f1);
      r.z = x2*cosf(f2) + sgn*p2*sinf(f2);
      r.w = x3*cosf(f3) + sgn*p3*sinf(f3);
      ((float4*)qsh)[t] = r;
    }
    if (t < 64){    // k: per-head rms + rope -> ksh ; v passthrough -> vsh
      const int idx16 = t & 15;
      float4 k = ((const float4*)(p.qkv + 1024))[t];
      float ss = grp16_sum(dot4(k,k));
      const float inv = rsqrtf(ss*(1.0f/HDIM) + EPSF);
      float4 w = ((const float4*)(p.kn + l*HDIM))[idx16];
      float x0=k.x*inv*w.x, x1=k.y*inv*w.y, x2=k.z*inv*w.z, x3=k.w*inv*w.w;
      float p0=__shfl_xor(x0,8), p1=__shfl_xor(x1,8), p2=__shfl_xor(x2,8), p3=__shfl_xor(x3,8);
      const int d0 = idx16*4;
      const bool lolane = (idx16 < 8);
      const int m = lolane ? d0 : d0-32;
      const float f0=p.invf[m]*pos, f1=p.invf[m+1]*pos, f2=p.invf[m+2]*pos, f3=p.invf[m+3]*pos;
      const float sgn = lolane ? -1.f : 1.f;
      float4 r;
      r.x = x0*cosf(f0) + sgn*p0*sinf(f0);
      r.y = x1*cosf(f1) + sgn*p1*sinf(f1);
      r.z = x2*cosf(f2) + sgn*p2*sinf(f2);
      r.w = x3*cosf(f3) + sgn*p3*sinf(f3);
      ((float4*)ksh)[t] = r;
      float4 v = ((const float4*)(p.qkv + 1280))[t];
      ((float4*)vsh)[t] = v;
      if (b == 0){
        ((float4*)(p.knew + l*KVDIM))[t] = r;
        ((float4*)(p.vnew + l*KVDIM))[t] = v;
      }
    }
    __syncthreads();
    if (t < 256){   // scores + softmax
      const int h = t>>4, s = t&15, kvh = h>>2;
      const float um = umsh[s], pm = pmsh[s];
      const float* kcol = kc_l + (size_t)(kvh*HDIM)*SS + s;
      const float* ksrc = ksh + kvh*HDIM;
      const float* qv   = qsh + h*HDIM;
      float dot = 0.f;
      #pragma unroll
      for (int d=0; d<HDIM; d++){
        float kc = kcol[d*SS]*(1.f-um) + ksrc[d]*um;
        dot += qv[d]*kc;
      }
      const float sc = dot*0.125f + pm;
      const float mx = grp16_max(sc);
      const float e  = expf(sc-mx);
      const float sm = grp16_sum(e);
      awsh[t] = e/sm;
    }
    __syncthreads();
    if (t < 256){   // PV -> aosh
      const int h = t>>4, idx16 = t&15, kvh = h>>2;
      const int cb = kvh*HDIM + idx16*4;
      float a0=0,a1=0,a2=0,a3=0;
      #pragma unroll
      for (int s=0;s<SS;s++){
        const float aw = awsh[h*16+s];
        const float um = umsh[s];
        a0 += aw*(vc_l[(size_t)(cb+0)*SS+s]*(1.f-um)+vsh[cb+0]*um);
        a1 += aw*(vc_l[(size_t)(cb+1)*SS+s]*(1.f-um)+vsh[cb+1]*um);
        a2 += aw*(vc_l[(size_t)(cb+2)*SS+s]*(1.f-um)+vsh[cb+2]*um);
        a3 += aw*(vc_l[(size_t)(cb+3)*SS+s]*(1.f-um)+vsh[cb+3]*um);
      }
      ((float4*)aosh)[t] = make_float4(a0,a1,a2,a3);
    }
    __syncthreads();
    if (gw < 1024){  // Wo matvec + residual
      const float4* w4 = (const float4*)(Wo_l + (size_t)gw*DD);
      const float4* x4 = (const float4*)aosh;
      float acc = 0.f;
      #pragma unroll
      for (int j=0;j<4;j++) acc += dot4(w4[j*64+lane], x4[j*64+lane]);
      acc = wave_sum(acc);
      if (lane == 0) p.hidden[gw] = hsrc[gw] + acc;
    }
    grid.sync();

    // ======== stage 3: rms(ln2) + gate/up matvec + silu*mul (4096 rows) ========
    {
      float hv = p.hidden[t];
      float ss = wave_sum(hv*hv);
      if (lane == 0) red[wid] = ss;
      __syncthreads();
      float tot = 0.f;
      #pragma unroll
      for (int i=0;i<16;i++) tot += red[i];
      const float inv = rsqrtf(tot*(1.0f/DD) + EPSF);
      xs[t] = hv*inv*p.ln2[l*DD + t];
      __syncthreads();
    }
    {
      const float4* g4 = (const float4*)(Wg_l + (size_t)gw*DD);
      const float4* u4 = (const float4*)(Wu_l + (size_t)gw*DD);
      const float4* x4 = (const float4*)xs;
      float ag=0.f, au=0.f;
      #pragma unroll
      for (int j=0;j<4;j++){
        float4 x = x4[j*64+lane];
        ag += dot4(g4[j*64+lane], x);
        au += dot4(u4[j*64+lane], x);
      }
      ag = wave_sum(ag); au = wave_sum(au);
      if (lane == 0) p.act[gw] = (ag/(1.f+expf(-ag)))*au;
    }
    grid.sync();

    // ======== stage 4: Wdown matvec (1024 rows, K=4096) + residual ========
    ((float4*)xs)[t] = ((const float4*)p.act)[t];
    __syncthreads();
    if (gw < 1024){
      const float4* w4 = (const float4*)(Wd_l + (size_t)gw*FDIM);
      const float4* x4 = (const float4*)xs;
      float acc = 0.f;
      #pragma unroll
      for (int j=0;j<16;j++) acc += dot4(w4[j*64+lane], x4[j*64+lane]);
      acc = wave_sum(acc);
      if (lane == 0) p.hidden[gw] += acc;
    }
    grid.sync();
  }

  // ======== final: rms(norm_w) + outputs + lm_head ========
  {
    float hv = p.hidden[t];
    float ss = wave_sum(hv*hv);
    if (lane == 0) red[wid] = ss;
    __syncthreads();
    float tot = 0.f;
    #pragma unroll
    for (int i=0;i<16;i++) tot += red[i];
    const float inv = rsqrtf(tot*(1.0f/DD) + EPSF);
    xs[t] = hv*inv*p.nw[t];
    __syncthreads();
  }
  if (b == 0) p.out_hidden[t] = xs[t];
  if (t < 192){   // nkc/nvc assembly: 49152 elems, 192 per block
    const int j = b*192 + t;
    if (j < NLAYER*KVDIM*SS){
      const int s = j & 15, c = j >> 4;
      const float um = p.umask[s];
      p.out_nkc[j] = p.kcache[j]*(1.f-um) + p.knew[c]*um;
    } else {
      const int i = j - NLAYER*KVDIM*SS;
      const int s = i & 15, c = i >> 4;
      const float um = p.umask[s];
      p.out_nvc[i] = p.vcache[i]*(1.f-um) + p.vnew[c]*um;
    }
  }
  {
    const float4* x4 = (const float4*)xs;
    #pragma unroll 1
    for (int k=0;k<NCODE;k++){
      const int row = k*4096 + gw;
      const float4* w4 = (const float4*)(p.lmw + (size_t)row*DD);
      float acc = 0.f;
      #pragma unroll
      for (int j=0;j<4;j++) acc += dot4(w4[j*64+lane], x4[j*64+lane]);
      acc = wave_sum(acc);
      if (lane == 0) p.out_logits[row] = acc;
    }
  }
}

extern "C" void kernel_launch(void* const* d_in, const int* in_sizes, int n_in,
                              void* d_out, int out_size, void* d_ws, size_t ws_size,
                              hipStream_t stream)
{
  KP hp;
  hp.emb    = (const float*)d_in[0];
  hp.clen   = (const int*)  d_in[1];
  hp.kcache = (const float*)d_in[2];
  hp.pmask  = (const float*)d_in[3];
  hp.umask  = (const float*)d_in[4];
  hp.vcache = (const float*)d_in[5];
  hp.invf   = (const float*)d_in[6];
  hp.Wq     = (const float*)d_in[7];
  hp.Wk     = (const float*)d_in[8];
  hp.Wv     = (const float*)d_in[9];
  hp.Wo     = (const float*)d_in[10];
  hp.ln1    = (const float*)d_in[11];
  hp.ln2    = (const float*)d_in[12];
  hp.qn     = (const float*)d_in[13];
  hp.kn     = (const float*)d_in[14];
  hp.Wg     = (const float*)d_in[15];
  hp.Wu     = (const float*)d_in[16];
  hp.Wd     = (const float*)d_in[17];
  hp.nw     = (const float*)d_in[18];
  hp.lmw    = (const float*)d_in[19];

  float* ws = (float*)d_ws;
  hp.hidden = ws;            // 1024
  hp.qkv    = ws + 1024;     // 1536
  hp.act    = ws + 2560;     // 4096
  hp.knew   = ws + 6656;     // 1536
  hp.vnew   = ws + 8192;     // 1536

  float* out = (float*)d_out;
  hp.out_logits = out;                       // 61440
  hp.out_hidden = out + NCODE*VDIM;          // 1024
  hp.out_nkc    = hp.out_hidden + DD;        // 24576
  hp.out_nvc    = hp.out_nkc + NLAYER*KVDIM*SS; // 24576

  void* args[] = { &hp };
  hipLaunchCooperativeKernel((const void*)k_decode, dim3(256), dim3(1024),
                             args, 0, stream);
}